// Round 6
// baseline (476.349 us; speedup 1.0000x reference)
//
#include <hip/hip_runtime.h>

typedef unsigned short u16;
typedef unsigned int u32;
typedef float vf4 __attribute__((ext_vector_type(4)));
typedef unsigned int vu4 __attribute__((ext_vector_type(4)));
typedef short sh8 __attribute__((ext_vector_type(8)));
typedef float f32x4 __attribute__((ext_vector_type(4)));

// ---------- bf16 helpers ----------
__device__ __forceinline__ float bf2f(u16 u) {
  return __uint_as_float(((u32)u) << 16);
}
__device__ __forceinline__ u16 f2bf(float f) {
  u32 x = __float_as_uint(f);
  return (u16)((x + 0x7fffu + ((x >> 16) & 1u)) >> 16);
}
__device__ __forceinline__ float ldin(const void* p, int idx, int isf) {
  return isf ? ((const float*)p)[idx] : bf2f(((const u16*)p)[idx]);
}

// ---------- workspace layout (bytes) ----------
// wTh1 129 pitch rows (p=128 = zeros), wTm1 129 rows: branchless gather.
#define OFF_FLAG  ((size_t)0)
#define OFF_WB    ((size_t)16)
#define OFF_WTH1  ((size_t)1180432)     // 99072 f32 (incl. zero row)
#define OFF_WTM1  ((size_t)1576720)     // 41280 f32 (incl. zero row)
#define OFF_COMB  ((size_t)1741840)     // 16384 f32
#define OFF_FEATF ((size_t)1807376)     // 16384 f32
#define OFF_FEATB ((size_t)1872912)     // 16384 u16
// --- diagnostic scratch (unused gap 1.91 MB .. 18.6 MB) ---
#define OFF_COMB2 ((size_t)3000000)     // scratch combined (probe)
#define OFF_DP2   ((size_t)3100000)     // scratch dpws (probe)
#define OFF_DP    ((size_t)18686736)    // 32*16*128 f32
#define OFF_WH2B  ((size_t)52536080)    // 32*512 u16 hi
#define OFF_WH2L  ((size_t)52568848)    // 32*512 u16 lo
#define OFF_WM2B  ((size_t)52601616)    // 32*192 u16 hi
#define OFF_WM2L  ((size_t)52613904)    // 32*192 u16 lo
#define WS_NEEDED ((size_t)52626192)

// weight-bank float offsets
#define WB_R1W 0
#define WB_R1B 256
#define WB_R2W 288
#define WB_R2B 8480
#define WB_H1B 8544
#define WB_H2W 8608
#define WB_H2B 24992
#define WB_M1B 25024
#define WB_M2W 25088
#define WB_M2B 31232
#define WB_D1W 31264
#define WB_D1B 31648
#define WB_D2W 31664
#define WB_D2B 32432
#define WB_FCW 32448
#define WB_FCB 294592
#define WB_TOTAL 295104

// k_convert j-ranges
#define CV_TH1_END 394176   // WB_TOTAL + 99072
#define CV_TM1_END 435456   // + 41280
#define CV_CMB_END 451840   // + 16384
#define CV_WH2_END 468224   // + 16384
#define CV_TOTAL   474368   // + 6144

// ---------- convert weights (detect folded in: each block recomputes flag) ----------
__global__ __launch_bounds__(256) void k_convert(
    const void* r1_w, const void* r1_b, const void* r2_w, const void* r2_b,
    const void* h1_w, const void* h1_b, const void* h2_w, const void* h2_b,
    const void* m1_w, const void* m1_b, const void* m2_w, const void* m2_b,
    const void* d1_w, const void* d1_b, const void* d2_w, const void* d2_b,
    const void* fc_w, const void* fc_b,
    int* __restrict__ flagp, float* __restrict__ wb,
    float* __restrict__ wTh1, float* __restrict__ wTm1,
    float* __restrict__ combined,
    u16* __restrict__ wh2b, u16* __restrict__ wh2l,
    u16* __restrict__ wm2b, u16* __restrict__ wm2l) {
  __shared__ int cnt[4];
  int tid = threadIdx.x;
  {
    u16 v = ((const u16*)fc_w)[2 * tid];
    int e = (v >> 7) & 0xFF;
    int outside = (e < 100 || e > 140) ? 1 : 0;
    unsigned long long m = __ballot(outside);
    if ((tid & 63) == 0) cnt[tid >> 6] = __popcll(m);
  }
  __syncthreads();
  int isf = (cnt[0] + cnt[1] + cnt[2] + cnt[3] >= 64) ? 1 : 0;
  if (blockIdx.x == 0 && tid == 0) flagp[0] = isf;   // for k_bcast

  int j = blockIdx.x * 256 + tid;
  if (j >= CV_TOTAL) return;
  if (j < WB_TOTAL) {
    const void* src; int si;
    if      (j < WB_R1B) { src = r1_w; si = j; }
    else if (j < WB_R2W) { src = r1_b; si = j - WB_R1B; }
    else if (j < WB_R2B) { src = r2_w; si = j - WB_R2W; }
    else if (j < WB_H1B) { src = r2_b; si = j - WB_R2B; }
    else if (j < WB_H2W) { src = h1_b; si = j - WB_H1B; }
    else if (j < WB_H2B) { src = h2_w; si = j - WB_H2W; }
    else if (j < WB_M1B) { src = h2_b; si = j - WB_H2B; }
    else if (j < WB_M2W) { src = m1_b; si = j - WB_M1B; }
    else if (j < WB_M2B) { src = m2_w; si = j - WB_M2W; }
    else if (j < WB_D1W) { src = m2_b; si = j - WB_M2B; }
    else if (j < WB_D1B) { src = d1_w; si = j - WB_D1W; }
    else if (j < WB_D2W) { src = d1_b; si = j - WB_D1B; }
    else if (j < WB_D2B) { src = d2_w; si = j - WB_D2W; }
    else if (j < WB_FCW) { src = d2_b; si = j - WB_D2B; }
    else if (j < WB_FCB) { src = fc_w; si = j - WB_FCW; }
    else                 { src = fc_b; si = j - WB_FCB; }
    wb[j] = ldin(src, si, isf);
  } else if (j < CV_TH1_END) {
    int j2 = j - WB_TOTAL;
    int o = j2 & 63, r = j2 >> 6;                  // r = p*12+k, p in [0,129)
    wTh1[j2] = (r >= 1536) ? 0.f : ldin(h1_w, (o * 128 + r / 12) * 12 + (r % 12), isf);
  } else if (j < CV_TM1_END) {
    int j3 = j - CV_TH1_END;
    int o = j3 & 63, r = j3 >> 6;                  // r = p*5+k
    wTm1[j3] = (r >= 640) ? 0.f : ldin(m1_w, (o * 128 + r / 5) * 5 + (r % 5), isf);
  } else if (j < CV_CMB_END) {
    combined[j - CV_TM1_END] = 0.f;
  } else if (j < CV_WH2_END) {
    int jj = j - CV_CMB_END;               // [o*512 + c*8 + kk], o in [0,32)
    int o = jj >> 9, rem = jj & 511, c = rem >> 3, kk = rem & 7;
    float w = ldin(h2_w, (o * 64 + c) * 8 + kk, isf);
    u16 hi = f2bf(w);
    wh2b[jj] = hi;
    wh2l[jj] = f2bf(w - bf2f(hi));
  } else {
    int jj = j - CV_WH2_END;               // [o*192 + c*3 + kk], o in [0,32)
    int o = jj / 192, rem = jj % 192, c = rem / 3, kk = rem % 3;
    float w = ldin(m2_w, (o * 64 + c) * 3 + kk, isf);
    u16 hi = f2bf(w);
    wm2b[jj] = hi;
    wm2l[jj] = f2bf(w - bf2f(hi));
  }
}

// ================= single fused conv1+conv2 kernel =================
// Branchless conv1 gather: token staging stores pre-clamped, pre-scaled table
// offsets; inactive taps hit a zero row (x + 0.0f == x -> bit-exact).

#define HT_STRIDE 142   // u16 row stride for h tile (71 dwords)
#define MT_STRIDE 133   // u16 row stride for m tile (128-t chunks)

// ---- fused H: conv1-h (K=12) + conv2-h MFMA + pool ----
// 1024 blocks: chunk in [0,8), q in [0,4), b in [0,32). tb = q*512+chunk*64.
__device__ __forceinline__ void dev_hf(float* smem, const int* tok,
                                       const float* wTh1, const float* h1bf,
                                       const u16* wh2b, const u16* wh2l,
                                       const float* h2bf,
                                       float* combined, int chunk, int q, int b) {
  u16* htile = (u16*)smem;                    // [64][HT_STRIDE] u16
  int* tks = (int*)(smem + 4544);             // 146 table offsets
  const int tid = threadIdx.x;
  const int tb = q * 512 + chunk * 64;
  const int sg0 = 2 * tb;
  const int* tokb = tok + b * 4096;
  if (tid < 146) {
    int x = sg0 - 9 + tid;                    // = (2tb-3) - 6 + tid
    int p = ((unsigned)x < 4096u) ? tokb[x] : 128;
    tks[tid] = (p < 128 ? p : 128) * 768;     // row base in wTh1 (p*12*64)
  }
  __syncthreads();
  {
    const int og = tid & 15, slot = tid >> 4;
    const float4 bias = *(const float4*)(h1bf + og * 4);
    const float* wbase = wTh1 + og * 4;
    for (int pos = slot; pos < 134; pos += 16) {
      int t = sg0 - 3 + pos;
      u16 o0 = 0, o1 = 0, o2 = 0, o3 = 0;
      if ((unsigned)t <= 4096u) {
        float4 acc = bias;
#pragma unroll
        for (int k = 0; k < 12; ++k) {
          const float4 wv = *(const float4*)(wbase + tks[pos + k] + k * 64);
          acc.x += wv.x; acc.y += wv.y; acc.z += wv.z; acc.w += wv.w;
        }
        o0 = f2bf(fmaxf(acc.x, 0.f)); o1 = f2bf(fmaxf(acc.y, 0.f));
        o2 = f2bf(fmaxf(acc.z, 0.f)); o3 = f2bf(fmaxf(acc.w, 0.f));
      }
      int rb = og * 4 * HT_STRIDE + pos;
      htile[rb] = o0;
      htile[rb + HT_STRIDE] = o1;
      htile[rb + 2 * HT_STRIDE] = o2;
      htile[rb + 3 * HT_STRIDE] = o3;
    }
  }
  __syncthreads();
  // conv2-h MFMA (hoisted weight frags per kc): waves (ot,tp)
  const int w = tid >> 6, l = tid & 63;
  const int quad = l >> 4, n = l & 15;
  const int ot = w & 1, tp = w >> 1;
  f32x4 acc2[2];
  acc2[0] = (f32x4){0.f, 0.f, 0.f, 0.f};
  acc2[1] = (f32x4){0.f, 0.f, 0.f, 0.f};
  const u16* wph = wh2b + (size_t)(16 * ot + n) * 512 + quad * 8;
  const u16* wpl = wh2l + (size_t)(16 * ot + n) * 512 + quad * 8;
  const u32* hp = (const u32*)htile;
  for (int kc = 0; kc < 2; ++kc) {
    sh8 ah[8], al[8];
#pragma unroll
    for (int s = 0; s < 8; ++s) {
      ah[s] = *(const sh8*)(wph + kc * 256 + 32 * s);
      al[s] = *(const sh8*)(wpl + kc * 256 + 32 * s);
    }
#pragma unroll
    for (int it = 0; it < 2; ++it) {
      int fb = 16 * (2 * it + tp) + n;        // dword index within a row
#pragma unroll
      for (int s = 0; s < 8; ++s) {
        int c = kc * 32 + 4 * s + quad;
        const u32* p = hp + c * 71 + fb;
        u32 bw[4] = {p[0], p[1], p[2], p[3]};
        sh8 bb;
        __builtin_memcpy(&bb, bw, 16);
        acc2[it] = __builtin_amdgcn_mfma_f32_16x16x32_bf16(ah[s], bb, acc2[it], 0, 0, 0);
        acc2[it] = __builtin_amdgcn_mfma_f32_16x16x32_bf16(al[s], bb, acc2[it], 0, 0, 0);
      }
    }
  }
#pragma unroll
  for (int r = 0; r < 4; ++r) {
    float bsv = h2bf[16 * ot + quad * 4 + r];
    float s = fmaxf(acc2[0][r] + bsv, 0.f) + fmaxf(acc2[1][r] + bsv, 0.f);
    s += __shfl_xor(s, 1, 64);
    s += __shfl_xor(s, 2, 64);
    s += __shfl_xor(s, 4, 64);
    s += __shfl_xor(s, 8, 64);
    if (n == 0) {
      int o = 16 * ot + quad * 4 + r;
      atomicAdd(&combined[b * 512 + 128 + 4 * o + q], s * (1.f / 512.f));
    }
  }
}

// ---- fused M: conv1-m (K=5) + conv2-m MFMA + pool (128-t chunks) ----
// 1024 blocks: sub in [0,8), q in [0,4), b in [0,32). tb = q*1024+sub*128.
__device__ __forceinline__ void dev_mf(float* smem, const int* tok,
                                       const float* wTm1, const float* m1bf,
                                       const u16* wm2b, const u16* wm2l,
                                       const float* m2bf,
                                       float* combined, int sub, int q, int b) {
  u16* mtile = (u16*)smem;                    // [64][MT_STRIDE]
  int* tks = (int*)(smem + 4256);             // 135 table offsets
  const int tid = threadIdx.x;
  const int tb = q * 1024 + sub * 128;
  const int* tokb = tok + b * 4096;
  if (tid < 135) {
    int x = tb - 4 + tid;
    int p = ((unsigned)x < 4096u) ? tokb[x] : 128;
    tks[tid] = (p < 128 ? p : 128) * 320;     // row base in wTm1 (p*5*64)
  }
  __syncthreads();
  {
    const int og = tid & 15, slot = tid >> 4;
    const float4 bias = *(const float4*)(m1bf + og * 4);
    const float* wbase = wTm1 + og * 4;
    for (int u = slot; u < 131; u += 16) {
      int t = tb - 2 + u;
      u16 o0 = 0, o1 = 0, o2 = 0, o3 = 0;
      if ((unsigned)t < 4096u) {
        float4 acc = bias;
#pragma unroll
        for (int k = 0; k < 5; ++k) {
          const float4 wv = *(const float4*)(wbase + tks[u + k] + k * 64);
          acc.x += wv.x; acc.y += wv.y; acc.z += wv.z; acc.w += wv.w;
        }
        o0 = f2bf(fmaxf(acc.x, 0.f)); o1 = f2bf(fmaxf(acc.y, 0.f));
        o2 = f2bf(fmaxf(acc.z, 0.f)); o3 = f2bf(fmaxf(acc.w, 0.f));
      }
      int rb = og * 4 * MT_STRIDE + u;
      mtile[rb] = o0;
      mtile[rb + MT_STRIDE] = o1;
      mtile[rb + 2 * MT_STRIDE] = o2;
      mtile[rb + 3 * MT_STRIDE] = o3;
    }
  }
  __syncthreads();
  const int w = tid >> 6, l = tid & 63;
  const int quad = l >> 4, n = l & 15;
  const int ot = w & 1, tp = w >> 1;
  sh8 ah[6], al[6];
  {
    const u16* wph = wm2b + (size_t)(16 * ot + n) * 192 + quad * 8;
    const u16* wpl = wm2l + (size_t)(16 * ot + n) * 192 + quad * 8;
#pragma unroll
    for (int s = 0; s < 6; ++s) {
      ah[s] = *(const sh8*)(wph + 32 * s);
      al[s] = *(const sh8*)(wpl + 32 * s);
    }
  }
  float bsv[4];
#pragma unroll
  for (int r = 0; r < 4; ++r) bsv[r] = m2bf[16 * ot + quad * 4 + r];
  float sm[4] = {0.f, 0.f, 0.f, 0.f};
  const int gkb = quad * 8;
  for (int it = 0; it < 4; ++it) {
    int ub = 16 * (2 * it + tp) + n + 1;      // u = (t0-tb)+n+kk+1
    f32x4 acc = {0.f, 0.f, 0.f, 0.f};
#pragma unroll
    for (int s = 0; s < 6; ++s) {
      sh8 bb;
#pragma unroll
      for (int j = 0; j < 8; ++j) {
        int gk = 32 * s + gkb + j;
        int c = (gk * 21846) >> 16;           // gk / 3
        int kk = gk - 3 * c;
        bb[j] = (short)mtile[c * MT_STRIDE + ub + kk];
      }
      acc = __builtin_amdgcn_mfma_f32_16x16x32_bf16(ah[s], bb, acc, 0, 0, 0);
      acc = __builtin_amdgcn_mfma_f32_16x16x32_bf16(al[s], bb, acc, 0, 0, 0);
    }
#pragma unroll
    for (int r = 0; r < 4; ++r) sm[r] += fmaxf(acc[r] + bsv[r], 0.f);
  }
#pragma unroll
  for (int r = 0; r < 4; ++r) {
    float s = sm[r];
    s += __shfl_xor(s, 1, 64);
    s += __shfl_xor(s, 2, 64);
    s += __shfl_xor(s, 4, 64);
    s += __shfl_xor(s, 8, 64);
    if (n == 0) {
      int o = 16 * ot + quad * 4 + r;
      atomicAdd(&combined[b * 512 + 256 + 4 * o + q], s * (1.f / 1024.f));
    }
  }
}

// ---- fused R: conv1-r (binary indicator, K=8, stride2) + conv2-r + pool ----
// 512 blocks: chunk in [0,16), b. r1 window: r1t[o][xi] = r1[o][2*tbase-2+xi], xi in [0,134).
__device__ __forceinline__ void dev_rf(float* smem, const int* tok,
                                       const float* r1wf, const float* r1bf,
                                       const float* r2wf, const float* r2bf,
                                       float* combined, int chunk, int b) {
  float* w1s = smem;              // 256
  float* b1s = smem + 256;        // 32
  float* Ibuf = smem + 288;       // 270
  float* r1t = smem + 560;        // 32*134 = 4288
  float* wcr = smem + 4848;       // 2048
  const int tid = threadIdx.x;
  const int tbase = chunk * 64;
  const int tk0 = 4 * tbase - 7;
  const int* tokb = tok + b * 4096;
  w1s[tid] = r1wf[tid];
  if (tid < 32) b1s[tid] = r1bf[tid];
  for (int i = tid; i < 270; i += 256) {
    int x = tk0 + i;
    float v = 0.f;
    if ((unsigned)x < 4096u) {
      int tk = tokb[x];
      v = (tk >= 256 && tk < 768) ? 1.f : 0.f;
    }
    Ibuf[i] = v;
  }
  __syncthreads();
  {
    const int tl1 = tid & 63, og1 = tid >> 6;
    for (int xi = tl1; xi < 134; xi += 64) {
      int x = 2 * tbase - 2 + xi;
      if ((unsigned)x < 2048u) {
        float iv[8];
#pragma unroll
        for (int k = 0; k < 8; ++k) iv[k] = Ibuf[2 * xi + k];
#pragma unroll
        for (int i = 0; i < 8; ++i) {
          int o = og1 * 8 + i;
          float a = b1s[o];
#pragma unroll
          for (int k = 0; k < 8; ++k) a = fmaf(w1s[o * 8 + k], iv[k], a);
          r1t[o * 134 + xi] = fmaxf(a, 0.f);
        }
      } else {
#pragma unroll
        for (int i = 0; i < 8; ++i) r1t[(og1 * 8 + i) * 134 + xi] = 0.f;
      }
    }
  }
  __syncthreads();
  const int half = chunk >> 3;
  const int og = tid >> 6, tl = tid & 63;
  float acc[16];
#pragma unroll
  for (int i = 0; i < 16; ++i) acc[i] = 0.f;
  for (int c0 = 0; c0 < 32; c0 += 8) {
    for (int f = tid; f < 2048; f += 256) {
      int o = f & 63, r = f >> 6, k = r & 3, cc = r >> 2;
      wcr[f] = r2wf[(o * 32 + c0 + cc) * 4 + k];
    }
    __syncthreads();
#pragma unroll
    for (int cc = 0; cc < 8; ++cc) {
      const float* rr = r1t + (c0 + cc) * 134 + 2 * tl;
      float ev[3], od[3];
#pragma unroll
      for (int f3 = 0; f3 < 3; ++f3) {
        ev[f3] = rr[2 * f3];
        od[f3] = rr[2 * f3 + 1];
      }
#pragma unroll
      for (int k = 0; k < 4; ++k) {
        const int p = (k + 1) & 1, fk = (k + 1) >> 1;
        const float* wv = &wcr[(cc * 4 + k) * 64 + og * 16];
        float4 wa = *(const float4*)wv;
        float4 wbv = *(const float4*)(wv + 4);
        float4 wcc = *(const float4*)(wv + 8);
        float4 wd4 = *(const float4*)(wv + 12);
        float wr[16] = {wa.x, wa.y, wa.z, wa.w, wbv.x, wbv.y, wbv.z, wbv.w,
                        wcc.x, wcc.y, wcc.z, wcc.w, wd4.x, wd4.y, wd4.z, wd4.w};
        float v0 = p ? od[fk] : ev[fk];
#pragma unroll
        for (int i = 0; i < 16; ++i) acc[i] = fmaf(v0, wr[i], acc[i]);
      }
    }
    __syncthreads();
  }
  const float inv = 1.f / 512.f;
#pragma unroll
  for (int i = 0; i < 16; ++i) {
    int o = og * 16 + i;
    float s = fmaxf(acc[i] + r2bf[o], 0.f);
#pragma unroll
    for (int d = 32; d > 0; d >>= 1) s += __shfl_down(s, d, 64);
    if (tl == 0) atomicAdd(&combined[b * 512 + 2 * o + half], s * inv);
  }
}

// ---- fused D: conv1-d (class select, K=4, branchless 7-class table) + conv2-d + pool ----
// 1024 blocks: chunk in [0,32), b. dt[c][iu] = d1[c][tbase-1+iu], iu in [0,131).
__device__ __forceinline__ void dev_df(float* smem, const int* tok,
                                       const float* d1wf, const float* d1bf,
                                       const float* d2wf, const float* d2bf,
                                       float* dpws, int chunk, int b) {
  float* wds7 = smem;                 // 16*7*4 = 448 (class 6 = zeros)
  float* wd = smem + 448;             // 768
  int* cls = (int*)(smem + 1216);     // 136
  float (*dt)[132] = reinterpret_cast<float(*)[132]>(smem + 1352);  // 16x132
  float* c2 = smem + 3464;            // 16 rows, stride 133
  const int tid = threadIdx.x;
  const int tbase = chunk * 128;
  const int* tokb = tok + b * 4096;
  for (int f = tid; f < 448; f += 256) {
    int k = f & 3, rest = f >> 2, v = rest % 7, c = rest / 7;
    wds7[f] = (v < 6) ? d1wf[(c * 6 + v) * 4 + k] : 0.f;
  }
  for (int f = tid; f < 768; f += 256) wd[f] = d2wf[f];
  if (tid < 136) {
    int x = tbase - 3 + tid;
    int v = 6;
    if ((unsigned)x < 4096u) {
      int tk = tokb[x];
      if (tk >= 768) { v = tk - 768; v = v > 5 ? 5 : v; } else v = 6;
    }
    cls[tid] = v;
  }
  __syncthreads();
  for (int f = tid; f < 16 * 131; f += 256) {
    int iu = f % 131, c = f / 131;
    int x = tbase - 1 + iu;
    float v = 0.f;
    if (x >= 0 && x <= 4096) {
      float a = d1bf[c];
#pragma unroll
      for (int k = 0; k < 4; ++k) {
        a += wds7[(c * 7 + cls[iu + k]) * 4 + k];
      }
      v = fmaxf(a, 0.f);
    }
    dt[c][iu] = v;
  }
  __syncthreads();
  for (int idx = tid; idx < 16 * 129; idx += 256) {
    int o = idx / 129, tl = idx % 129;
    float a = d2bf[o];
    const float* ww = &wd[o * 48];
#pragma unroll 4
    for (int c = 0; c < 16; ++c) {
      a = fmaf(dt[c][tl], ww[c * 3 + 0],
          fmaf(dt[c][tl + 1], ww[c * 3 + 1],
          fmaf(dt[c][tl + 2], ww[c * 3 + 2], a)));
    }
    c2[o * 133 + tl] = fmaxf(a, 0.f);
  }
  __syncthreads();
  if (tid < 64) {
    int o = tid >> 2, qq = tid & 3;
    const float* row = c2 + o * 133 + 32 * qq;
    float s = 0.f;
#pragma unroll
    for (int j = 0; j < 33; ++j) s += row[j];
    dpws[(size_t)(b * 16 + o) * 128 + 4 * chunk + qq] = s * (1.f / 33.f);
  }
}

__global__ __launch_bounds__(256, 4) void k_fused(const int* __restrict__ tok,
                                                  const float* __restrict__ wb,
                                                  const float* __restrict__ wTh1,
                                                  const float* __restrict__ wTm1,
                                                  const u16* __restrict__ wh2b,
                                                  const u16* __restrict__ wh2l,
                                                  const u16* __restrict__ wm2b,
                                                  const u16* __restrict__ wm2l,
                                                  float* __restrict__ combined,
                                                  float* __restrict__ dpws) {
  __shared__ __align__(16) float smem[6896];   // 27584 B (r-family max)
  int bx = blockIdx.x;
  if (bx < 1024) {
    dev_hf(smem, tok, wTh1, wb + WB_H1B, wh2b, wh2l, wb + WB_H2B, combined,
           bx & 7, (bx >> 3) & 3, bx >> 5);
  } else if (bx < 2048) {
    int n = bx - 1024;
    dev_mf(smem, tok, wTm1, wb + WB_M1B, wm2b, wm2l, wb + WB_M2B, combined,
           n & 7, (n >> 3) & 3, n >> 5);
  } else if (bx < 2560) {
    int n = bx - 2048;
    dev_rf(smem, tok, wb + WB_R1W, wb + WB_R1B, wb + WB_R2W, wb + WB_R2B,
           combined, n & 15, n >> 4);
  } else {
    int n = bx - 2560;
    dev_df(smem, tok, wb + WB_D1W, wb + WB_D1B, wb + WB_D2W, wb + WB_D2B,
           dpws, n & 31, n >> 5);
  }
}

// ---------- FC (+ fused dynamics final pool) ----------
// 256 blocks: b = bx>>3, oct = bx&7; 64 outputs/block, 4 lanes per output.
__global__ __launch_bounds__(256) void k_fc(const float* __restrict__ combined,
                                            const float* __restrict__ dpws,
                                            const float* __restrict__ fcwf,
                                            const float* __restrict__ fcbf,
                                            float* __restrict__ featf,
                                            u16* __restrict__ featb) {
  const int bx = blockIdx.x;
  const int b = bx >> 3, oct = bx & 7;
  const int tid = threadIdx.x;
  __shared__ float cb[512];
  cb[tid] = combined[b * 512 + tid];
  if (tid < 128) {
    cb[256 + tid] = combined[b * 512 + 256 + tid];
  } else {
    int j = tid - 128;                 // [0,128) -> combined[384..512)
    int o = j >> 3, i0 = (j & 7) * 16;
    const float* row = dpws + (size_t)(b * 16 + o) * 128;
    float s = 0.f;
#pragma unroll
    for (int i = 0; i < 16; ++i) s += row[i0 + i];
    cb[384 + j] = s * (1.f / 16.f);
  }
  __syncthreads();
  const int oo = oct * 64 + (tid >> 2), part = tid & 3;
  float acc = 0.f;
  const float4* wr = (const float4*)(fcwf + (size_t)oo * 512 + part * 128);
#pragma unroll 8
  for (int j4 = 0; j4 < 32; ++j4) {
    float4 w = wr[j4];
    const float* c4 = &cb[part * 128 + j4 * 4];
    acc = fmaf(c4[0], w.x, acc);
    acc = fmaf(c4[1], w.y, acc);
    acc = fmaf(c4[2], w.z, acc);
    acc = fmaf(c4[3], w.w, acc);
  }
  acc += __shfl_xor(acc, 1, 64);
  acc += __shfl_xor(acc, 2, 64);
  if (part == 0) {
    float r = acc + fcbf[oo];
    featf[b * 512 + oo] = r;
    featb[b * 512 + oo] = f2bf(r);
  }
}

// ---------- broadcast (nontemporal; bf16 path uses all blocks) ----------
__global__ __launch_bounds__(256) void k_bcast(const int* __restrict__ flagp,
                                               const vf4* __restrict__ featf4,
                                               const vu4* __restrict__ featb4,
                                               vf4* __restrict__ outf,
                                               vu4* __restrict__ outb) {
  if (flagp[0]) {
    int base = blockIdx.x * 1024 + threadIdx.x;
#pragma unroll
    for (int s = 0; s < 4; ++s) {
      int g = base + s * 256;        // 16777216 vf4 total
      vf4 v = featf4[(g >> 19) * 128 + (g & 127)];
      __builtin_nontemporal_store(v, &outf[g]);
    }
  } else {
    int base = blockIdx.x * 512 + threadIdx.x;
#pragma unroll
    for (int s = 0; s < 2; ++s) {
      int g = base + s * 256;        // 8388608 vu4 total
      vu4 v = featb4[(g >> 18) * 64 + (g & 63)];
      __builtin_nontemporal_store(v, &outb[g]);
    }
  }
}

extern "C" void kernel_launch(void* const* d_in, const int* in_sizes, int n_in,
                              void* d_out, int out_size, void* d_ws, size_t ws_size,
                              hipStream_t stream) {
  if (ws_size < WS_NEEDED) return;

  const int* tokens = (const int*)d_in[0];
  const void* r1_w = d_in[1];  const void* r1_b = d_in[2];
  const void* r2_w = d_in[3];  const void* r2_b = d_in[4];
  const void* h1_w = d_in[5];  const void* h1_b = d_in[6];
  const void* h2_w = d_in[7];  const void* h2_b = d_in[8];
  const void* m1_w = d_in[9];  const void* m1_b = d_in[10];
  const void* m2_w = d_in[11]; const void* m2_b = d_in[12];
  const void* d1_w = d_in[13]; const void* d1_b = d_in[14];
  const void* d2_w = d_in[15]; const void* d2_b = d_in[16];
  const void* fc_w = d_in[17]; const void* fc_b = d_in[18];

  char* ws = (char*)d_ws;
  int*   flagp   = (int*)  (ws + OFF_FLAG);
  float* wb      = (float*)(ws + OFF_WB);
  float* wTh1    = (float*)(ws + OFF_WTH1);
  float* wTm1    = (float*)(ws + OFF_WTM1);
  float* combined= (float*)(ws + OFF_COMB);
  float* featf   = (float*)(ws + OFF_FEATF);
  u16*   featb   = (u16*)  (ws + OFF_FEATB);
  float* dpws    = (float*)(ws + OFF_DP);
  float* comb2   = (float*)(ws + OFF_COMB2);   // probe scratch (never read)
  float* dpws2   = (float*)(ws + OFF_DP2);     // probe scratch (never read)
  u16*   wh2b    = (u16*)  (ws + OFF_WH2B);
  u16*   wh2l    = (u16*)  (ws + OFF_WH2L);
  u16*   wm2b    = (u16*)  (ws + OFF_WM2B);
  u16*   wm2l    = (u16*)  (ws + OFF_WM2L);

  k_convert<<<1853, 256, 0, stream>>>(r1_w, r1_b, r2_w, r2_b, h1_w, h1_b, h2_w, h2_b,
                                      m1_w, m1_b, m2_w, m2_b, d1_w, d1_b, d2_w, d2_b,
                                      fc_w, fc_b, flagp, wb, wTh1, wTm1, combined,
                                      wh2b, wh2l, wm2b, wm2l);
  // ---- DIAGNOSTIC PROBE: duplicate k_fused into scratch outputs.
  // dur_r6 - dur_r5 = T_fused + one kernel boundary. Remove next round.
  k_fused<<<3584, 256, 0, stream>>>(tokens, wb, wTh1, wTm1, wh2b, wh2l, wm2b, wm2l,
                                    comb2, dpws2);
  // ---- real pipeline (unchanged from round 5) ----
  k_fused<<<3584, 256, 0, stream>>>(tokens, wb, wTh1, wTm1, wh2b, wh2l, wm2b, wm2l,
                                    combined, dpws);
  k_fc<<<256, 256, 0, stream>>>(combined, dpws, wb + WB_FCW, wb + WB_FCB, featf, featb);
  k_bcast<<<16384, 256, 0, stream>>>(flagp, (const vf4*)featf, (const vu4*)featb,
                                     (vf4*)d_out, (vu4*)d_out);
}

// Round 7
// 403.173 us; speedup vs baseline: 1.1815x; 1.1815x over previous
//
#include <hip/hip_runtime.h>

typedef unsigned short u16;
typedef unsigned int u32;
typedef float vf4 __attribute__((ext_vector_type(4)));
typedef unsigned int vu4 __attribute__((ext_vector_type(4)));
typedef short sh8 __attribute__((ext_vector_type(8)));
typedef float f32x4 __attribute__((ext_vector_type(4)));

// ---------- bf16 helpers ----------
__device__ __forceinline__ float bf2f(u16 u) {
  return __uint_as_float(((u32)u) << 16);
}
__device__ __forceinline__ u16 f2bf(float f) {
  u32 x = __float_as_uint(f);
  return (u16)((x + 0x7fffu + ((x >> 16) & 1u)) >> 16);
}
__device__ __forceinline__ float ldin(const void* p, int idx, int isf) {
  return isf ? ((const float*)p)[idx] : bf2f(((const u16*)p)[idx]);
}

// ---------- workspace layout (bytes) ----------
// wTh1 129 pitch rows (p=128 = zeros), wTm1 129 rows: branchless gather.
#define OFF_FLAG  ((size_t)0)
#define OFF_WB    ((size_t)16)
#define OFF_WTH1  ((size_t)1180432)     // 99072 f32 (incl. zero row)
#define OFF_WTM1  ((size_t)1576720)     // 41280 f32 (incl. zero row)
#define OFF_COMB  ((size_t)1741840)     // 16384 f32
#define OFF_DP    ((size_t)18686736)    // 32*16*128 f32
#define OFF_WH2B  ((size_t)52536080)    // 32*512 u16 hi
#define OFF_WH2L  ((size_t)52568848)    // 32*512 u16 lo
#define OFF_WM2B  ((size_t)52601616)    // 32*192 u16 hi
#define OFF_WM2L  ((size_t)52613904)    // 32*192 u16 lo
#define WS_NEEDED ((size_t)52626192)

// weight-bank float offsets
#define WB_R1W 0
#define WB_R1B 256
#define WB_R2W 288
#define WB_R2B 8480
#define WB_H1B 8544
#define WB_H2W 8608
#define WB_H2B 24992
#define WB_M1B 25024
#define WB_M2W 25088
#define WB_M2B 31232
#define WB_D1W 31264
#define WB_D1B 31648
#define WB_D2W 31664
#define WB_D2B 32432
#define WB_FCW 32448
#define WB_FCB 294592
#define WB_TOTAL 295104

// k_convert j-ranges
#define CV_TH1_END 394176   // WB_TOTAL + 99072
#define CV_TM1_END 435456   // + 41280
#define CV_CMB_END 451840   // + 16384
#define CV_WH2_END 468224   // + 16384
#define CV_TOTAL   474368   // + 6144

// ---------- convert weights (detect folded in: each block recomputes flag) ----------
__global__ __launch_bounds__(256) void k_convert(
    const void* r1_w, const void* r1_b, const void* r2_w, const void* r2_b,
    const void* h1_w, const void* h1_b, const void* h2_w, const void* h2_b,
    const void* m1_w, const void* m1_b, const void* m2_w, const void* m2_b,
    const void* d1_w, const void* d1_b, const void* d2_w, const void* d2_b,
    const void* fc_w, const void* fc_b,
    int* __restrict__ flagp, float* __restrict__ wb,
    float* __restrict__ wTh1, float* __restrict__ wTm1,
    float* __restrict__ combined,
    u16* __restrict__ wh2b, u16* __restrict__ wh2l,
    u16* __restrict__ wm2b, u16* __restrict__ wm2l) {
  __shared__ int cnt[4];
  int tid = threadIdx.x;
  {
    u16 v = ((const u16*)fc_w)[2 * tid];
    int e = (v >> 7) & 0xFF;
    int outside = (e < 100 || e > 140) ? 1 : 0;
    unsigned long long m = __ballot(outside);
    if ((tid & 63) == 0) cnt[tid >> 6] = __popcll(m);
  }
  __syncthreads();
  int isf = (cnt[0] + cnt[1] + cnt[2] + cnt[3] >= 64) ? 1 : 0;
  if (blockIdx.x == 0 && tid == 0) flagp[0] = isf;   // for k_out

  int j = blockIdx.x * 256 + tid;
  if (j >= CV_TOTAL) return;
  if (j < WB_TOTAL) {
    const void* src; int si;
    if      (j < WB_R1B) { src = r1_w; si = j; }
    else if (j < WB_R2W) { src = r1_b; si = j - WB_R1B; }
    else if (j < WB_R2B) { src = r2_w; si = j - WB_R2W; }
    else if (j < WB_H1B) { src = r2_b; si = j - WB_R2B; }
    else if (j < WB_H2W) { src = h1_b; si = j - WB_H1B; }
    else if (j < WB_H2B) { src = h2_w; si = j - WB_H2W; }
    else if (j < WB_M1B) { src = h2_b; si = j - WB_H2B; }
    else if (j < WB_M2W) { src = m1_b; si = j - WB_M1B; }
    else if (j < WB_M2B) { src = m2_w; si = j - WB_M2W; }
    else if (j < WB_D1W) { src = m2_b; si = j - WB_M2B; }
    else if (j < WB_D1B) { src = d1_w; si = j - WB_D1W; }
    else if (j < WB_D2W) { src = d1_b; si = j - WB_D1B; }
    else if (j < WB_D2B) { src = d2_w; si = j - WB_D2W; }
    else if (j < WB_FCW) { src = d2_b; si = j - WB_D2B; }
    else if (j < WB_FCB) { src = fc_w; si = j - WB_FCW; }
    else                 { src = fc_b; si = j - WB_FCB; }
    wb[j] = ldin(src, si, isf);
  } else if (j < CV_TH1_END) {
    int j2 = j - WB_TOTAL;
    int o = j2 & 63, r = j2 >> 6;                  // r = p*12+k, p in [0,129)
    wTh1[j2] = (r >= 1536) ? 0.f : ldin(h1_w, (o * 128 + r / 12) * 12 + (r % 12), isf);
  } else if (j < CV_TM1_END) {
    int j3 = j - CV_TH1_END;
    int o = j3 & 63, r = j3 >> 6;                  // r = p*5+k
    wTm1[j3] = (r >= 640) ? 0.f : ldin(m1_w, (o * 128 + r / 5) * 5 + (r % 5), isf);
  } else if (j < CV_CMB_END) {
    combined[j - CV_TM1_END] = 0.f;
  } else if (j < CV_WH2_END) {
    int jj = j - CV_CMB_END;               // [o*512 + c*8 + kk], o in [0,32)
    int o = jj >> 9, rem = jj & 511, c = rem >> 3, kk = rem & 7;
    float w = ldin(h2_w, (o * 64 + c) * 8 + kk, isf);
    u16 hi = f2bf(w);
    wh2b[jj] = hi;
    wh2l[jj] = f2bf(w - bf2f(hi));
  } else {
    int jj = j - CV_WH2_END;               // [o*192 + c*3 + kk], o in [0,32)
    int o = jj / 192, rem = jj % 192, c = rem / 3, kk = rem % 3;
    float w = ldin(m2_w, (o * 64 + c) * 3 + kk, isf);
    u16 hi = f2bf(w);
    wm2b[jj] = hi;
    wm2l[jj] = f2bf(w - bf2f(hi));
  }
}

// ================= single fused conv1+conv2 kernel =================
// Branchless conv1 gather: token staging stores pre-clamped, pre-scaled table
// offsets; inactive taps hit a zero row (x + 0.0f == x -> bit-exact).

#define HT_STRIDE 142   // u16 row stride for h tile (71 dwords)
#define MT_STRIDE 133   // u16 row stride for m tile (128-t chunks)

// ---- fused H: conv1-h (K=12) + conv2-h MFMA + pool ----
// 1024 idx: chunk in [0,8), q in [0,4), b in [0,32). tb = q*512+chunk*64.
__device__ __forceinline__ void dev_hf(float* smem, const int* tok,
                                       const float* wTh1, const float* h1bf,
                                       const u16* wh2b, const u16* wh2l,
                                       const float* h2bf,
                                       float* combined, int chunk, int q, int b) {
  u16* htile = (u16*)smem;                    // [64][HT_STRIDE] u16
  int* tks = (int*)(smem + 4544);             // 146 table offsets
  const int tid = threadIdx.x;
  const int tb = q * 512 + chunk * 64;
  const int sg0 = 2 * tb;
  const int* tokb = tok + b * 4096;
  if (tid < 146) {
    int x = sg0 - 9 + tid;                    // = (2tb-3) - 6 + tid
    int p = ((unsigned)x < 4096u) ? tokb[x] : 128;
    tks[tid] = (p < 128 ? p : 128) * 768;     // row base in wTh1 (p*12*64)
  }
  __syncthreads();
  {
    const int og = tid & 15, slot = tid >> 4;
    const float4 bias = *(const float4*)(h1bf + og * 4);
    const float* wbase = wTh1 + og * 4;
    for (int pos = slot; pos < 134; pos += 16) {
      int t = sg0 - 3 + pos;
      u16 o0 = 0, o1 = 0, o2 = 0, o3 = 0;
      if ((unsigned)t <= 4096u) {
        float4 acc = bias;
#pragma unroll
        for (int k = 0; k < 12; ++k) {
          const float4 wv = *(const float4*)(wbase + tks[pos + k] + k * 64);
          acc.x += wv.x; acc.y += wv.y; acc.z += wv.z; acc.w += wv.w;
        }
        o0 = f2bf(fmaxf(acc.x, 0.f)); o1 = f2bf(fmaxf(acc.y, 0.f));
        o2 = f2bf(fmaxf(acc.z, 0.f)); o3 = f2bf(fmaxf(acc.w, 0.f));
      }
      int rb = og * 4 * HT_STRIDE + pos;
      htile[rb] = o0;
      htile[rb + HT_STRIDE] = o1;
      htile[rb + 2 * HT_STRIDE] = o2;
      htile[rb + 3 * HT_STRIDE] = o3;
    }
  }
  __syncthreads();
  // conv2-h MFMA (hoisted weight frags per kc): waves (ot,tp)
  const int w = tid >> 6, l = tid & 63;
  const int quad = l >> 4, n = l & 15;
  const int ot = w & 1, tp = w >> 1;
  f32x4 acc2[2];
  acc2[0] = (f32x4){0.f, 0.f, 0.f, 0.f};
  acc2[1] = (f32x4){0.f, 0.f, 0.f, 0.f};
  const u16* wph = wh2b + (size_t)(16 * ot + n) * 512 + quad * 8;
  const u16* wpl = wh2l + (size_t)(16 * ot + n) * 512 + quad * 8;
  const u32* hp = (const u32*)htile;
  for (int kc = 0; kc < 2; ++kc) {
    sh8 ah[8], al[8];
#pragma unroll
    for (int s = 0; s < 8; ++s) {
      ah[s] = *(const sh8*)(wph + kc * 256 + 32 * s);
      al[s] = *(const sh8*)(wpl + kc * 256 + 32 * s);
    }
#pragma unroll
    for (int it = 0; it < 2; ++it) {
      int fb = 16 * (2 * it + tp) + n;        // dword index within a row
#pragma unroll
      for (int s = 0; s < 8; ++s) {
        int c = kc * 32 + 4 * s + quad;
        const u32* p = hp + c * 71 + fb;
        u32 bw[4] = {p[0], p[1], p[2], p[3]};
        sh8 bb;
        __builtin_memcpy(&bb, bw, 16);
        acc2[it] = __builtin_amdgcn_mfma_f32_16x16x32_bf16(ah[s], bb, acc2[it], 0, 0, 0);
        acc2[it] = __builtin_amdgcn_mfma_f32_16x16x32_bf16(al[s], bb, acc2[it], 0, 0, 0);
      }
    }
  }
#pragma unroll
  for (int r = 0; r < 4; ++r) {
    float bsv = h2bf[16 * ot + quad * 4 + r];
    float s = fmaxf(acc2[0][r] + bsv, 0.f) + fmaxf(acc2[1][r] + bsv, 0.f);
    s += __shfl_xor(s, 1, 64);
    s += __shfl_xor(s, 2, 64);
    s += __shfl_xor(s, 4, 64);
    s += __shfl_xor(s, 8, 64);
    if (n == 0) {
      int o = 16 * ot + quad * 4 + r;
      atomicAdd(&combined[b * 512 + 128 + 4 * o + q], s * (1.f / 512.f));
    }
  }
}

// ---- fused M: conv1-m (K=5) + conv2-m MFMA + pool (128-t chunks) ----
// 1024 idx: sub in [0,8), q in [0,4), b in [0,32). tb = q*1024+sub*128.
__device__ __forceinline__ void dev_mf(float* smem, const int* tok,
                                       const float* wTm1, const float* m1bf,
                                       const u16* wm2b, const u16* wm2l,
                                       const float* m2bf,
                                       float* combined, int sub, int q, int b) {
  u16* mtile = (u16*)smem;                    // [64][MT_STRIDE]
  int* tks = (int*)(smem + 4256);             // 135 table offsets
  const int tid = threadIdx.x;
  const int tb = q * 1024 + sub * 128;
  const int* tokb = tok + b * 4096;
  if (tid < 135) {
    int x = tb - 4 + tid;
    int p = ((unsigned)x < 4096u) ? tokb[x] : 128;
    tks[tid] = (p < 128 ? p : 128) * 320;     // row base in wTm1 (p*5*64)
  }
  __syncthreads();
  {
    const int og = tid & 15, slot = tid >> 4;
    const float4 bias = *(const float4*)(m1bf + og * 4);
    const float* wbase = wTm1 + og * 4;
    for (int u = slot; u < 131; u += 16) {
      int t = tb - 2 + u;
      u16 o0 = 0, o1 = 0, o2 = 0, o3 = 0;
      if ((unsigned)t < 4096u) {
        float4 acc = bias;
#pragma unroll
        for (int k = 0; k < 5; ++k) {
          const float4 wv = *(const float4*)(wbase + tks[u + k] + k * 64);
          acc.x += wv.x; acc.y += wv.y; acc.z += wv.z; acc.w += wv.w;
        }
        o0 = f2bf(fmaxf(acc.x, 0.f)); o1 = f2bf(fmaxf(acc.y, 0.f));
        o2 = f2bf(fmaxf(acc.z, 0.f)); o3 = f2bf(fmaxf(acc.w, 0.f));
      }
      int rb = og * 4 * MT_STRIDE + u;
      mtile[rb] = o0;
      mtile[rb + MT_STRIDE] = o1;
      mtile[rb + 2 * MT_STRIDE] = o2;
      mtile[rb + 3 * MT_STRIDE] = o3;
    }
  }
  __syncthreads();
  const int w = tid >> 6, l = tid & 63;
  const int quad = l >> 4, n = l & 15;
  const int ot = w & 1, tp = w >> 1;
  sh8 ah[6], al[6];
  {
    const u16* wph = wm2b + (size_t)(16 * ot + n) * 192 + quad * 8;
    const u16* wpl = wm2l + (size_t)(16 * ot + n) * 192 + quad * 8;
#pragma unroll
    for (int s = 0; s < 6; ++s) {
      ah[s] = *(const sh8*)(wph + 32 * s);
      al[s] = *(const sh8*)(wpl + 32 * s);
    }
  }
  float bsv[4];
#pragma unroll
  for (int r = 0; r < 4; ++r) bsv[r] = m2bf[16 * ot + quad * 4 + r];
  float sm[4] = {0.f, 0.f, 0.f, 0.f};
  const int gkb = quad * 8;
  for (int it = 0; it < 4; ++it) {
    int ub = 16 * (2 * it + tp) + n + 1;      // u = (t0-tb)+n+kk+1
    f32x4 acc = {0.f, 0.f, 0.f, 0.f};
#pragma unroll
    for (int s = 0; s < 6; ++s) {
      sh8 bb;
#pragma unroll
      for (int j = 0; j < 8; ++j) {
        int gk = 32 * s + gkb + j;
        int c = (gk * 21846) >> 16;           // gk / 3
        int kk = gk - 3 * c;
        bb[j] = (short)mtile[c * MT_STRIDE + ub + kk];
      }
      acc = __builtin_amdgcn_mfma_f32_16x16x32_bf16(ah[s], bb, acc, 0, 0, 0);
      acc = __builtin_amdgcn_mfma_f32_16x16x32_bf16(al[s], bb, acc, 0, 0, 0);
    }
#pragma unroll
    for (int r = 0; r < 4; ++r) sm[r] += fmaxf(acc[r] + bsv[r], 0.f);
  }
#pragma unroll
  for (int r = 0; r < 4; ++r) {
    float s = sm[r];
    s += __shfl_xor(s, 1, 64);
    s += __shfl_xor(s, 2, 64);
    s += __shfl_xor(s, 4, 64);
    s += __shfl_xor(s, 8, 64);
    if (n == 0) {
      int o = 16 * ot + quad * 4 + r;
      atomicAdd(&combined[b * 512 + 256 + 4 * o + q], s * (1.f / 1024.f));
    }
  }
}

// ---- fused R: conv1-r (binary indicator, K=8, stride2) + conv2-r + pool ----
// 512 idx: chunk in [0,16), b. r1 window: r1t[o][xi] = r1[o][2*tbase-2+xi], xi in [0,134).
__device__ __forceinline__ void dev_rf(float* smem, const int* tok,
                                       const float* r1wf, const float* r1bf,
                                       const float* r2wf, const float* r2bf,
                                       float* combined, int chunk, int b) {
  float* w1s = smem;              // 256
  float* b1s = smem + 256;        // 32
  float* Ibuf = smem + 288;       // 270
  float* r1t = smem + 560;        // 32*134 = 4288
  float* wcr = smem + 4848;       // 2048
  const int tid = threadIdx.x;
  const int tbase = chunk * 64;
  const int tk0 = 4 * tbase - 7;
  const int* tokb = tok + b * 4096;
  w1s[tid] = r1wf[tid];
  if (tid < 32) b1s[tid] = r1bf[tid];
  for (int i = tid; i < 270; i += 256) {
    int x = tk0 + i;
    float v = 0.f;
    if ((unsigned)x < 4096u) {
      int tk = tokb[x];
      v = (tk >= 256 && tk < 768) ? 1.f : 0.f;
    }
    Ibuf[i] = v;
  }
  __syncthreads();
  {
    const int tl1 = tid & 63, og1 = tid >> 6;
    for (int xi = tl1; xi < 134; xi += 64) {
      int x = 2 * tbase - 2 + xi;
      if ((unsigned)x < 2048u) {
        float iv[8];
#pragma unroll
        for (int k = 0; k < 8; ++k) iv[k] = Ibuf[2 * xi + k];
#pragma unroll
        for (int i = 0; i < 8; ++i) {
          int o = og1 * 8 + i;
          float a = b1s[o];
#pragma unroll
          for (int k = 0; k < 8; ++k) a = fmaf(w1s[o * 8 + k], iv[k], a);
          r1t[o * 134 + xi] = fmaxf(a, 0.f);
        }
      } else {
#pragma unroll
        for (int i = 0; i < 8; ++i) r1t[(og1 * 8 + i) * 134 + xi] = 0.f;
      }
    }
  }
  __syncthreads();
  const int half = chunk >> 3;
  const int og = tid >> 6, tl = tid & 63;
  float acc[16];
#pragma unroll
  for (int i = 0; i < 16; ++i) acc[i] = 0.f;
  for (int c0 = 0; c0 < 32; c0 += 8) {
    for (int f = tid; f < 2048; f += 256) {
      int o = f & 63, r = f >> 6, k = r & 3, cc = r >> 2;
      wcr[f] = r2wf[(o * 32 + c0 + cc) * 4 + k];
    }
    __syncthreads();
#pragma unroll
    for (int cc = 0; cc < 8; ++cc) {
      const float* rr = r1t + (c0 + cc) * 134 + 2 * tl;
      float ev[3], od[3];
#pragma unroll
      for (int f3 = 0; f3 < 3; ++f3) {
        ev[f3] = rr[2 * f3];
        od[f3] = rr[2 * f3 + 1];
      }
#pragma unroll
      for (int k = 0; k < 4; ++k) {
        const int p = (k + 1) & 1, fk = (k + 1) >> 1;
        const float* wv = &wcr[(cc * 4 + k) * 64 + og * 16];
        float4 wa = *(const float4*)wv;
        float4 wbv = *(const float4*)(wv + 4);
        float4 wcc = *(const float4*)(wv + 8);
        float4 wd4 = *(const float4*)(wv + 12);
        float wr[16] = {wa.x, wa.y, wa.z, wa.w, wbv.x, wbv.y, wbv.z, wbv.w,
                        wcc.x, wcc.y, wcc.z, wcc.w, wd4.x, wd4.y, wd4.z, wd4.w};
        float v0 = p ? od[fk] : ev[fk];
#pragma unroll
        for (int i = 0; i < 16; ++i) acc[i] = fmaf(v0, wr[i], acc[i]);
      }
    }
    __syncthreads();
  }
  const float inv = 1.f / 512.f;
#pragma unroll
  for (int i = 0; i < 16; ++i) {
    int o = og * 16 + i;
    float s = fmaxf(acc[i] + r2bf[o], 0.f);
#pragma unroll
    for (int d = 32; d > 0; d >>= 1) s += __shfl_down(s, d, 64);
    if (tl == 0) atomicAdd(&combined[b * 512 + 2 * o + half], s * inv);
  }
}

// ---- fused D: conv1-d (class select, K=4, branchless 7-class table) + conv2-d + pool ----
// 1024 idx: chunk in [0,32), b. dt[c][iu] = d1[c][tbase-1+iu], iu in [0,131).
__device__ __forceinline__ void dev_df(float* smem, const int* tok,
                                       const float* d1wf, const float* d1bf,
                                       const float* d2wf, const float* d2bf,
                                       float* dpws, int chunk, int b) {
  float* wds7 = smem;                 // 16*7*4 = 448 (class 6 = zeros)
  float* wd = smem + 448;             // 768
  int* cls = (int*)(smem + 1216);     // 136
  float (*dt)[132] = reinterpret_cast<float(*)[132]>(smem + 1352);  // 16x132
  float* c2 = smem + 3464;            // 16 rows, stride 133
  const int tid = threadIdx.x;
  const int tbase = chunk * 128;
  const int* tokb = tok + b * 4096;
  for (int f = tid; f < 448; f += 256) {
    int k = f & 3, rest = f >> 2, v = rest % 7, c = rest / 7;
    wds7[f] = (v < 6) ? d1wf[(c * 6 + v) * 4 + k] : 0.f;
  }
  for (int f = tid; f < 768; f += 256) wd[f] = d2wf[f];
  if (tid < 136) {
    int x = tbase - 3 + tid;
    int v = 6;
    if ((unsigned)x < 4096u) {
      int tk = tokb[x];
      if (tk >= 768) { v = tk - 768; v = v > 5 ? 5 : v; } else v = 6;
    }
    cls[tid] = v;
  }
  __syncthreads();
  for (int f = tid; f < 16 * 131; f += 256) {
    int iu = f % 131, c = f / 131;
    int x = tbase - 1 + iu;
    float v = 0.f;
    if (x >= 0 && x <= 4096) {
      float a = d1bf[c];
#pragma unroll
      for (int k = 0; k < 4; ++k) {
        a += wds7[(c * 7 + cls[iu + k]) * 4 + k];
      }
      v = fmaxf(a, 0.f);
    }
    dt[c][iu] = v;
  }
  __syncthreads();
  for (int idx = tid; idx < 16 * 129; idx += 256) {
    int o = idx / 129, tl = idx % 129;
    float a = d2bf[o];
    const float* ww = &wd[o * 48];
#pragma unroll 4
    for (int c = 0; c < 16; ++c) {
      a = fmaf(dt[c][tl], ww[c * 3 + 0],
          fmaf(dt[c][tl + 1], ww[c * 3 + 1],
          fmaf(dt[c][tl + 2], ww[c * 3 + 2], a)));
    }
    c2[o * 133 + tl] = fmaxf(a, 0.f);
  }
  __syncthreads();
  if (tid < 64) {
    int o = tid >> 2, qq = tid & 3;
    const float* row = c2 + o * 133 + 32 * qq;
    float s = 0.f;
#pragma unroll
    for (int j = 0; j < 33; ++j) s += row[j];
    dpws[(size_t)(b * 16 + o) * 128 + 4 * chunk + qq] = s * (1.f / 33.f);
  }
}

// Family-interleaved bx mapping: 3584 = 7*512; each group of 7 = 2h+2m+1r+2d
// so every scheduling wave mixes gather-heavy and FMA-heavy families.
__global__ __launch_bounds__(256, 4) void k_fused(const int* __restrict__ tok,
                                                  const float* __restrict__ wb,
                                                  const float* __restrict__ wTh1,
                                                  const float* __restrict__ wTm1,
                                                  const u16* __restrict__ wh2b,
                                                  const u16* __restrict__ wh2l,
                                                  const u16* __restrict__ wm2b,
                                                  const u16* __restrict__ wm2l,
                                                  float* __restrict__ combined,
                                                  float* __restrict__ dpws) {
  __shared__ __align__(16) float smem[6896];   // 27584 B (r-family max)
  int bx = blockIdx.x;
  int s7 = bx % 7, i7 = bx / 7;                // i7 in [0,512)
  if (s7 < 2) {
    int n = s7 * 512 + i7;                     // [0,1024)
    dev_hf(smem, tok, wTh1, wb + WB_H1B, wh2b, wh2l, wb + WB_H2B, combined,
           n & 7, (n >> 3) & 3, n >> 5);
  } else if (s7 < 4) {
    int n = (s7 - 2) * 512 + i7;               // [0,1024)
    dev_mf(smem, tok, wTm1, wb + WB_M1B, wm2b, wm2l, wb + WB_M2B, combined,
           n & 7, (n >> 3) & 3, n >> 5);
  } else if (s7 < 5) {
    int n = i7;                                // [0,512)
    dev_rf(smem, tok, wb + WB_R1W, wb + WB_R1B, wb + WB_R2W, wb + WB_R2B,
           combined, n & 15, n >> 4);
  } else {
    int n = (s7 - 5) * 512 + i7;               // [0,1024)
    dev_df(smem, tok, wb + WB_D1W, wb + WB_D1B, wb + WB_D2W, wb + WB_D2B,
           dpws, n & 31, n >> 5);
  }
}

// ---------- fused FC + broadcast ----------
// 2048 blocks: bx = b(32) x oct(8) x s8(8). Each block recomputes its 64 FC
// outputs (identical per-lane arithmetic to the old k_fc -> bit-exact) and
// streams its 512-row x 64-col output slice with nontemporal stores.
__global__ __launch_bounds__(256) void k_out(const int* __restrict__ flagp,
                                             const float* __restrict__ combined,
                                             const float* __restrict__ dpws,
                                             const float* __restrict__ fcwf,
                                             const float* __restrict__ fcbf,
                                             float* __restrict__ outf,
                                             u16* __restrict__ outb) {
  const int bx = blockIdx.x;
  const int s8 = bx & 7, oct = (bx >> 3) & 7, b = bx >> 6;
  const int tid = threadIdx.x;
  __shared__ float cb[512];
  __shared__ float feat[64];
  cb[tid] = combined[b * 512 + tid];
  if (tid < 128) {
    cb[256 + tid] = combined[b * 512 + 256 + tid];
  } else {
    int j = tid - 128;                 // [0,128) -> combined[384..512)
    int o = j >> 3, i0 = (j & 7) * 16;
    const float* row = dpws + (size_t)(b * 16 + o) * 128;
    float s = 0.f;
#pragma unroll
    for (int i = 0; i < 16; ++i) s += row[i0 + i];
    cb[384 + j] = s * (1.f / 16.f);
  }
  __syncthreads();
  const int oo = oct * 64 + (tid >> 2), part = tid & 3;
  float acc = 0.f;
  const float4* wr = (const float4*)(fcwf + (size_t)oo * 512 + part * 128);
#pragma unroll 8
  for (int j4 = 0; j4 < 32; ++j4) {
    float4 w = wr[j4];
    const float* c4 = &cb[part * 128 + j4 * 4];
    acc = fmaf(c4[0], w.x, acc);
    acc = fmaf(c4[1], w.y, acc);
    acc = fmaf(c4[2], w.z, acc);
    acc = fmaf(c4[3], w.w, acc);
  }
  acc += __shfl_xor(acc, 1, 64);
  acc += __shfl_xor(acc, 2, 64);
  if (part == 0) feat[tid >> 2] = acc + fcbf[oo];
  __syncthreads();
  // element base of this block's slice: out[b][s8*512 + s][oct*64 ...]
  const size_t obase = ((size_t)b * 4096 + (size_t)s8 * 512) * 512 + oct * 64;
  if (flagp[0]) {
    const int slot = tid & 15, rowg = tid >> 4;         // 16 slots x 16 rows
    float4 v4 = *(const float4*)&feat[slot * 4];
    vf4 vv; vv[0] = v4.x; vv[1] = v4.y; vv[2] = v4.z; vv[3] = v4.w;
    float* op = outf + obase + (size_t)rowg * 512 + slot * 4;
#pragma unroll 8
    for (int it = 0; it < 32; ++it) {
      __builtin_nontemporal_store(vv, (vf4*)(op + (size_t)it * 16 * 512));
    }
  } else {
    const int slot = tid & 7, rowg = tid >> 3;          // 8 slots x 32 rows
    u32 w0 = (u32)f2bf(feat[slot * 8 + 0]) | ((u32)f2bf(feat[slot * 8 + 1]) << 16);
    u32 w1 = (u32)f2bf(feat[slot * 8 + 2]) | ((u32)f2bf(feat[slot * 8 + 3]) << 16);
    u32 w2 = (u32)f2bf(feat[slot * 8 + 4]) | ((u32)f2bf(feat[slot * 8 + 5]) << 16);
    u32 w3 = (u32)f2bf(feat[slot * 8 + 6]) | ((u32)f2bf(feat[slot * 8 + 7]) << 16);
    vu4 vv; vv[0] = w0; vv[1] = w1; vv[2] = w2; vv[3] = w3;
    u16* op = outb + obase + (size_t)rowg * 512 + slot * 8;
#pragma unroll 8
    for (int it = 0; it < 16; ++it) {
      __builtin_nontemporal_store(vv, (vu4*)(op + (size_t)it * 32 * 512));
    }
  }
}

extern "C" void kernel_launch(void* const* d_in, const int* in_sizes, int n_in,
                              void* d_out, int out_size, void* d_ws, size_t ws_size,
                              hipStream_t stream) {
  if (ws_size < WS_NEEDED) return;

  const int* tokens = (const int*)d_in[0];
  const void* r1_w = d_in[1];  const void* r1_b = d_in[2];
  const void* r2_w = d_in[3];  const void* r2_b = d_in[4];
  const void* h1_w = d_in[5];  const void* h1_b = d_in[6];
  const void* h2_w = d_in[7];  const void* h2_b = d_in[8];
  const void* m1_w = d_in[9];  const void* m1_b = d_in[10];
  const void* m2_w = d_in[11]; const void* m2_b = d_in[12];
  const void* d1_w = d_in[13]; const void* d1_b = d_in[14];
  const void* d2_w = d_in[15]; const void* d2_b = d_in[16];
  const void* fc_w = d_in[17]; const void* fc_b = d_in[18];

  char* ws = (char*)d_ws;
  int*   flagp   = (int*)  (ws + OFF_FLAG);
  float* wb      = (float*)(ws + OFF_WB);
  float* wTh1    = (float*)(ws + OFF_WTH1);
  float* wTm1    = (float*)(ws + OFF_WTM1);
  float* combined= (float*)(ws + OFF_COMB);
  float* dpws    = (float*)(ws + OFF_DP);
  u16*   wh2b    = (u16*)  (ws + OFF_WH2B);
  u16*   wh2l    = (u16*)  (ws + OFF_WH2L);
  u16*   wm2b    = (u16*)  (ws + OFF_WM2B);
  u16*   wm2l    = (u16*)  (ws + OFF_WM2L);

  k_convert<<<1853, 256, 0, stream>>>(r1_w, r1_b, r2_w, r2_b, h1_w, h1_b, h2_w, h2_b,
                                      m1_w, m1_b, m2_w, m2_b, d1_w, d1_b, d2_w, d2_b,
                                      fc_w, fc_b, flagp, wb, wTh1, wTm1, combined,
                                      wh2b, wh2l, wm2b, wm2l);
  k_fused<<<3584, 256, 0, stream>>>(tokens, wb, wTh1, wTm1, wh2b, wh2l, wm2b, wm2l,
                                    combined, dpws);
  k_out<<<2048, 256, 0, stream>>>(flagp, combined, dpws, wb + WB_FCW, wb + WB_FCB,
                                  (float*)d_out, (u16*)d_out);
}

// Round 8
// 390.823 us; speedup vs baseline: 1.2188x; 1.0316x over previous
//
#include <hip/hip_runtime.h>

typedef unsigned short u16;
typedef unsigned int u32;
typedef float vf4 __attribute__((ext_vector_type(4)));
typedef unsigned int vu4 __attribute__((ext_vector_type(4)));
typedef short sh8 __attribute__((ext_vector_type(8)));
typedef float f32x4 __attribute__((ext_vector_type(4)));

// ---------- bf16 helpers ----------
__device__ __forceinline__ float bf2f(u16 u) {
  return __uint_as_float(((u32)u) << 16);
}
__device__ __forceinline__ u16 f2bf(float f) {
  u32 x = __float_as_uint(f);
  return (u16)((x + 0x7fffu + ((x >> 16) & 1u)) >> 16);
}
__device__ __forceinline__ float ldin(const void* p, int idx, int isf) {
  return isf ? ((const float*)p)[idx] : bf2f(((const u16*)p)[idx]);
}

// ---------- workspace layout (bytes) ----------
// wTh1 129 pitch rows (p=128 = zeros), wTm1 129 rows: branchless gather.
#define OFF_FLAG  ((size_t)0)
#define OFF_WB    ((size_t)16)
#define OFF_WTH1  ((size_t)1180432)     // 99072 f32 (incl. zero row)
#define OFF_WTM1  ((size_t)1576720)     // 41280 f32 (incl. zero row)
#define OFF_COMB  ((size_t)1741840)     // 16384 f32
#define OFF_FEATF ((size_t)1807376)     // 16384 f32
#define OFF_FEATB ((size_t)1872912)     // 16384 u16
#define OFF_DP    ((size_t)18686736)    // 32*16*128 f32
#define OFF_WH2B  ((size_t)52536080)    // 32*512 u16 hi
#define OFF_WH2L  ((size_t)52568848)    // 32*512 u16 lo
#define OFF_WM2B  ((size_t)52601616)    // [kk][o][c] 3*32*64 u16 hi
#define OFF_WM2L  ((size_t)52613904)    // [kk][o][c] 3*32*64 u16 lo
#define WS_NEEDED ((size_t)52626192)

// weight-bank float offsets
#define WB_R1W 0
#define WB_R1B 256
#define WB_R2W 288
#define WB_R2B 8480
#define WB_H1B 8544
#define WB_H2W 8608
#define WB_H2B 24992
#define WB_M1B 25024
#define WB_M2W 25088
#define WB_M2B 31232
#define WB_D1W 31264
#define WB_D1B 31648
#define WB_D2W 31664
#define WB_D2B 32432
#define WB_FCW 32448
#define WB_FCB 294592
#define WB_TOTAL 295104

// k_convert j-ranges
#define CV_TH1_END 394176   // WB_TOTAL + 99072
#define CV_TM1_END 435456   // + 41280
#define CV_CMB_END 451840   // + 16384
#define CV_WH2_END 468224   // + 16384
#define CV_TOTAL   474368   // + 6144

// ---------- convert weights (detect folded in: each block recomputes flag) ----------
__global__ __launch_bounds__(256) void k_convert(
    const void* r1_w, const void* r1_b, const void* r2_w, const void* r2_b,
    const void* h1_w, const void* h1_b, const void* h2_w, const void* h2_b,
    const void* m1_w, const void* m1_b, const void* m2_w, const void* m2_b,
    const void* d1_w, const void* d1_b, const void* d2_w, const void* d2_b,
    const void* fc_w, const void* fc_b,
    int* __restrict__ flagp, float* __restrict__ wb,
    float* __restrict__ wTh1, float* __restrict__ wTm1,
    float* __restrict__ combined,
    u16* __restrict__ wh2b, u16* __restrict__ wh2l,
    u16* __restrict__ wm2b, u16* __restrict__ wm2l) {
  __shared__ int cnt[4];
  int tid = threadIdx.x;
  {
    u16 v = ((const u16*)fc_w)[2 * tid];
    int e = (v >> 7) & 0xFF;
    int outside = (e < 100 || e > 140) ? 1 : 0;
    unsigned long long m = __ballot(outside);
    if ((tid & 63) == 0) cnt[tid >> 6] = __popcll(m);
  }
  __syncthreads();
  int isf = (cnt[0] + cnt[1] + cnt[2] + cnt[3] >= 64) ? 1 : 0;
  if (blockIdx.x == 0 && tid == 0) flagp[0] = isf;   // for k_bcast

  int j = blockIdx.x * 256 + tid;
  if (j >= CV_TOTAL) return;
  if (j < WB_TOTAL) {
    const void* src; int si;
    if      (j < WB_R1B) { src = r1_w; si = j; }
    else if (j < WB_R2W) { src = r1_b; si = j - WB_R1B; }
    else if (j < WB_R2B) { src = r2_w; si = j - WB_R2W; }
    else if (j < WB_H1B) { src = r2_b; si = j - WB_R2B; }
    else if (j < WB_H2W) { src = h1_b; si = j - WB_H1B; }
    else if (j < WB_H2B) { src = h2_w; si = j - WB_H2W; }
    else if (j < WB_M1B) { src = h2_b; si = j - WB_H2B; }
    else if (j < WB_M2W) { src = m1_b; si = j - WB_M1B; }
    else if (j < WB_M2B) { src = m2_w; si = j - WB_M2W; }
    else if (j < WB_D1W) { src = m2_b; si = j - WB_M2B; }
    else if (j < WB_D1B) { src = d1_w; si = j - WB_D1W; }
    else if (j < WB_D2W) { src = d1_b; si = j - WB_D1B; }
    else if (j < WB_D2B) { src = d2_w; si = j - WB_D2W; }
    else if (j < WB_FCW) { src = d2_b; si = j - WB_D2B; }
    else if (j < WB_FCB) { src = fc_w; si = j - WB_FCW; }
    else                 { src = fc_b; si = j - WB_FCB; }
    wb[j] = ldin(src, si, isf);
  } else if (j < CV_TH1_END) {
    int j2 = j - WB_TOTAL;
    int o = j2 & 63, r = j2 >> 6;                  // r = p*12+k, p in [0,129)
    wTh1[j2] = (r >= 1536) ? 0.f : ldin(h1_w, (o * 128 + r / 12) * 12 + (r % 12), isf);
  } else if (j < CV_TM1_END) {
    int j3 = j - CV_TH1_END;
    int o = j3 & 63, r = j3 >> 6;                  // r = p*5+k
    wTm1[j3] = (r >= 640) ? 0.f : ldin(m1_w, (o * 128 + r / 5) * 5 + (r % 5), isf);
  } else if (j < CV_CMB_END) {
    combined[j - CV_TM1_END] = 0.f;
  } else if (j < CV_WH2_END) {
    int jj = j - CV_CMB_END;               // [o*512 + c*8 + kk], o in [0,32)
    int o = jj >> 9, rem = jj & 511, c = rem >> 3, kk = rem & 7;
    float w = ldin(h2_w, (o * 64 + c) * 8 + kk, isf);
    u16 hi = f2bf(w);
    wh2b[jj] = hi;
    wh2l[jj] = f2bf(w - bf2f(hi));
  } else {
    int jj = j - CV_WH2_END;               // NEW layout: [kk*2048 + o*64 + c]
    int kk = jj >> 11, rem = jj & 2047, o = rem >> 6, c = rem & 63;
    float w = ldin(m2_w, (o * 64 + c) * 3 + kk, isf);
    u16 hi = f2bf(w);
    wm2b[jj] = hi;
    wm2l[jj] = f2bf(w - bf2f(hi));
  }
}

// ================= single fused conv1+conv2 kernel =================
// Branchless conv1 gather: token staging stores pre-clamped, pre-scaled table
// offsets; inactive taps hit a zero row (x + 0.0f == x -> bit-exact).

#define HT_STRIDE 142   // u16 row stride for h tile (71 dwords)
#define MT2_STRIDE 72   // u16 row stride for transposed m tile [u][c] (16B-aligned rows)

// ---- fused H: conv1-h (K=12) + conv2-h MFMA + pool ----
// 1024 blocks: chunk in [0,8), q in [0,4), b in [0,32). tb = q*512+chunk*64.
__device__ __forceinline__ void dev_hf(float* smem, const int* tok,
                                       const float* wTh1, const float* h1bf,
                                       const u16* wh2b, const u16* wh2l,
                                       const float* h2bf,
                                       float* combined, int chunk, int q, int b) {
  u16* htile = (u16*)smem;                    // [64][HT_STRIDE] u16
  int* tks = (int*)(smem + 4544);             // 146 table offsets
  const int tid = threadIdx.x;
  const int tb = q * 512 + chunk * 64;
  const int sg0 = 2 * tb;
  const int* tokb = tok + b * 4096;
  if (tid < 146) {
    int x = sg0 - 9 + tid;                    // = (2tb-3) - 6 + tid
    int p = ((unsigned)x < 4096u) ? tokb[x] : 128;
    tks[tid] = (p < 128 ? p : 128) * 768;     // row base in wTh1 (p*12*64)
  }
  __syncthreads();
  {
    const int og = tid & 15, slot = tid >> 4;
    const float4 bias = *(const float4*)(h1bf + og * 4);
    const float* wbase = wTh1 + og * 4;
    for (int pos = slot; pos < 134; pos += 16) {
      int t = sg0 - 3 + pos;
      u16 o0 = 0, o1 = 0, o2 = 0, o3 = 0;
      if ((unsigned)t <= 4096u) {
        float4 acc = bias;
#pragma unroll
        for (int k = 0; k < 12; ++k) {
          const float4 wv = *(const float4*)(wbase + tks[pos + k] + k * 64);
          acc.x += wv.x; acc.y += wv.y; acc.z += wv.z; acc.w += wv.w;
        }
        o0 = f2bf(fmaxf(acc.x, 0.f)); o1 = f2bf(fmaxf(acc.y, 0.f));
        o2 = f2bf(fmaxf(acc.z, 0.f)); o3 = f2bf(fmaxf(acc.w, 0.f));
      }
      int rb = og * 4 * HT_STRIDE + pos;
      htile[rb] = o0;
      htile[rb + HT_STRIDE] = o1;
      htile[rb + 2 * HT_STRIDE] = o2;
      htile[rb + 3 * HT_STRIDE] = o3;
    }
  }
  __syncthreads();
  // conv2-h MFMA (hoisted weight frags per kc): waves (ot,tp)
  const int w = tid >> 6, l = tid & 63;
  const int quad = l >> 4, n = l & 15;
  const int ot = w & 1, tp = w >> 1;
  f32x4 acc2[2];
  acc2[0] = (f32x4){0.f, 0.f, 0.f, 0.f};
  acc2[1] = (f32x4){0.f, 0.f, 0.f, 0.f};
  const u16* wph = wh2b + (size_t)(16 * ot + n) * 512 + quad * 8;
  const u16* wpl = wh2l + (size_t)(16 * ot + n) * 512 + quad * 8;
  const u32* hp = (const u32*)htile;
  for (int kc = 0; kc < 2; ++kc) {
    sh8 ah[8], al[8];
#pragma unroll
    for (int s = 0; s < 8; ++s) {
      ah[s] = *(const sh8*)(wph + kc * 256 + 32 * s);
      al[s] = *(const sh8*)(wpl + kc * 256 + 32 * s);
    }
#pragma unroll
    for (int it = 0; it < 2; ++it) {
      int fb = 16 * (2 * it + tp) + n;        // dword index within a row
#pragma unroll
      for (int s = 0; s < 8; ++s) {
        int c = kc * 32 + 4 * s + quad;
        const u32* p = hp + c * 71 + fb;
        u32 bw[4] = {p[0], p[1], p[2], p[3]};
        sh8 bb;
        __builtin_memcpy(&bb, bw, 16);
        acc2[it] = __builtin_amdgcn_mfma_f32_16x16x32_bf16(ah[s], bb, acc2[it], 0, 0, 0);
        acc2[it] = __builtin_amdgcn_mfma_f32_16x16x32_bf16(al[s], bb, acc2[it], 0, 0, 0);
      }
    }
  }
#pragma unroll
  for (int r = 0; r < 4; ++r) {
    float bsv = h2bf[16 * ot + quad * 4 + r];
    float s = fmaxf(acc2[0][r] + bsv, 0.f) + fmaxf(acc2[1][r] + bsv, 0.f);
    s += __shfl_xor(s, 1, 64);
    s += __shfl_xor(s, 2, 64);
    s += __shfl_xor(s, 4, 64);
    s += __shfl_xor(s, 8, 64);
    if (n == 0) {
      int o = 16 * ot + quad * 4 + r;
      atomicAdd(&combined[b * 512 + 128 + 4 * o + q], s * (1.f / 512.f));
    }
  }
}

// ---- fused M: conv1-m (K=5) + conv2-m MFMA + pool (128-t chunks) ----
// 1024 blocks: sub in [0,8), q in [0,4), b in [0,32). tb = q*1024+sub*128.
// TRANSPOSED tile: mtileT[u][c], u in [0,131), stride 72 u16 (rows 16B-aligned).
// conv2-m runs as 3 kk-shifted K=64 GEMMs: B-fragment = one ds_read_b128.
__device__ __forceinline__ void dev_mf(float* smem, const int* tok,
                                       const float* wTm1, const float* m1bf,
                                       const u16* wm2b, const u16* wm2l,
                                       const float* m2bf,
                                       float* combined, int sub, int q, int b) {
  u16* mT = (u16*)smem;                       // [131][MT2_STRIDE] = 18864 B
  int* tks = (int*)(smem + 4716);             // 135 table offsets
  const int tid = threadIdx.x;
  const int tb = q * 1024 + sub * 128;
  const int* tokb = tok + b * 4096;
  if (tid < 135) {
    int x = tb - 4 + tid;
    int p = ((unsigned)x < 4096u) ? tokb[x] : 128;
    tks[tid] = (p < 128 ? p : 128) * 320;     // row base in wTm1 (p*5*64)
  }
  __syncthreads();
  {
    const int og = tid & 15, slot = tid >> 4;
    const float4 bias = *(const float4*)(m1bf + og * 4);
    const float* wbase = wTm1 + og * 4;
    for (int u = slot; u < 131; u += 16) {
      int t = tb - 2 + u;
      u16 o0 = 0, o1 = 0, o2 = 0, o3 = 0;
      if ((unsigned)t < 4096u) {
        float4 acc = bias;
#pragma unroll
        for (int k = 0; k < 5; ++k) {
          const float4 wv = *(const float4*)(wbase + tks[u + k] + k * 64);
          acc.x += wv.x; acc.y += wv.y; acc.z += wv.z; acc.w += wv.w;
        }
        o0 = f2bf(fmaxf(acc.x, 0.f)); o1 = f2bf(fmaxf(acc.y, 0.f));
        o2 = f2bf(fmaxf(acc.z, 0.f)); o3 = f2bf(fmaxf(acc.w, 0.f));
      }
      uint2 pack;
      pack.x = (u32)o0 | ((u32)o1 << 16);
      pack.y = (u32)o2 | ((u32)o3 << 16);
      *(uint2*)&mT[u * MT2_STRIDE + og * 4] = pack;   // 8B-aligned store
    }
  }
  __syncthreads();
  const int w = tid >> 6, l = tid & 63;
  const int quad = l >> 4, n = l & 15;
  const int ot = w & 1, tp = w >> 1;
  sh8 ah[3][2], al[3][2];
  {
    const u16* wph = wm2b + (size_t)(16 * ot + n) * 64 + quad * 8;
    const u16* wpl = wm2l + (size_t)(16 * ot + n) * 64 + quad * 8;
#pragma unroll
    for (int kk = 0; kk < 3; ++kk) {
#pragma unroll
      for (int kc = 0; kc < 2; ++kc) {
        ah[kk][kc] = *(const sh8*)(wph + kk * 2048 + kc * 32);
        al[kk][kc] = *(const sh8*)(wpl + kk * 2048 + kc * 32);
      }
    }
  }
  float bsv[4];
#pragma unroll
  for (int r = 0; r < 4; ++r) bsv[r] = m2bf[16 * ot + quad * 4 + r];
  float sm[4] = {0.f, 0.f, 0.f, 0.f};
  for (int it = 0; it < 4; ++it) {
    const int un = 16 * (2 * it + tp) + n + 1;      // B row base
    f32x4 acc = {0.f, 0.f, 0.f, 0.f};
#pragma unroll
    for (int kk = 0; kk < 3; ++kk) {
      const u16* rowp = mT + (un + kk) * MT2_STRIDE + quad * 8;
#pragma unroll
      for (int kc = 0; kc < 2; ++kc) {
        sh8 bb = *(const sh8*)(rowp + kc * 32);     // 16B-aligned ds_read_b128
        acc = __builtin_amdgcn_mfma_f32_16x16x32_bf16(ah[kk][kc], bb, acc, 0, 0, 0);
        acc = __builtin_amdgcn_mfma_f32_16x16x32_bf16(al[kk][kc], bb, acc, 0, 0, 0);
      }
    }
#pragma unroll
    for (int r = 0; r < 4; ++r) sm[r] += fmaxf(acc[r] + bsv[r], 0.f);
  }
#pragma unroll
  for (int r = 0; r < 4; ++r) {
    float s = sm[r];
    s += __shfl_xor(s, 1, 64);
    s += __shfl_xor(s, 2, 64);
    s += __shfl_xor(s, 4, 64);
    s += __shfl_xor(s, 8, 64);
    if (n == 0) {
      int o = 16 * ot + quad * 4 + r;
      atomicAdd(&combined[b * 512 + 256 + 4 * o + q], s * (1.f / 1024.f));
    }
  }
}

// ---- fused R: conv1-r (binary indicator, K=8, stride2) + conv2-r + pool ----
// 512 blocks: chunk in [0,16), b. r1 window: r1t[o][xi] = r1[o][2*tbase-2+xi], xi in [0,134).
__device__ __forceinline__ void dev_rf(float* smem, const int* tok,
                                       const float* r1wf, const float* r1bf,
                                       const float* r2wf, const float* r2bf,
                                       float* combined, int chunk, int b) {
  float* w1s = smem;              // 256
  float* b1s = smem + 256;        // 32
  float* Ibuf = smem + 288;       // 270
  float* r1t = smem + 560;        // 32*134 = 4288
  float* wcr = smem + 4848;       // 2048
  const int tid = threadIdx.x;
  const int tbase = chunk * 64;
  const int tk0 = 4 * tbase - 7;
  const int* tokb = tok + b * 4096;
  w1s[tid] = r1wf[tid];
  if (tid < 32) b1s[tid] = r1bf[tid];
  for (int i = tid; i < 270; i += 256) {
    int x = tk0 + i;
    float v = 0.f;
    if ((unsigned)x < 4096u) {
      int tk = tokb[x];
      v = (tk >= 256 && tk < 768) ? 1.f : 0.f;
    }
    Ibuf[i] = v;
  }
  __syncthreads();
  {
    const int tl1 = tid & 63, og1 = tid >> 6;
    for (int xi = tl1; xi < 134; xi += 64) {
      int x = 2 * tbase - 2 + xi;
      if ((unsigned)x < 2048u) {
        float iv[8];
#pragma unroll
        for (int k = 0; k < 8; ++k) iv[k] = Ibuf[2 * xi + k];
#pragma unroll
        for (int i = 0; i < 8; ++i) {
          int o = og1 * 8 + i;
          float a = b1s[o];
#pragma unroll
          for (int k = 0; k < 8; ++k) a = fmaf(w1s[o * 8 + k], iv[k], a);
          r1t[o * 134 + xi] = fmaxf(a, 0.f);
        }
      } else {
#pragma unroll
        for (int i = 0; i < 8; ++i) r1t[(og1 * 8 + i) * 134 + xi] = 0.f;
      }
    }
  }
  __syncthreads();
  const int half = chunk >> 3;
  const int og = tid >> 6, tl = tid & 63;
  float acc[16];
#pragma unroll
  for (int i = 0; i < 16; ++i) acc[i] = 0.f;
  for (int c0 = 0; c0 < 32; c0 += 8) {
    for (int f = tid; f < 2048; f += 256) {
      int o = f & 63, r = f >> 6, k = r & 3, cc = r >> 2;
      wcr[f] = r2wf[(o * 32 + c0 + cc) * 4 + k];
    }
    __syncthreads();
#pragma unroll
    for (int cc = 0; cc < 8; ++cc) {
      const float* rr = r1t + (c0 + cc) * 134 + 2 * tl;
      float ev[3], od[3];
#pragma unroll
      for (int f3 = 0; f3 < 3; ++f3) {
        ev[f3] = rr[2 * f3];
        od[f3] = rr[2 * f3 + 1];
      }
#pragma unroll
      for (int k = 0; k < 4; ++k) {
        const int p = (k + 1) & 1, fk = (k + 1) >> 1;
        const float* wv = &wcr[(cc * 4 + k) * 64 + og * 16];
        float4 wa = *(const float4*)wv;
        float4 wbv = *(const float4*)(wv + 4);
        float4 wcc = *(const float4*)(wv + 8);
        float4 wd4 = *(const float4*)(wv + 12);
        float wr[16] = {wa.x, wa.y, wa.z, wa.w, wbv.x, wbv.y, wbv.z, wbv.w,
                        wcc.x, wcc.y, wcc.z, wcc.w, wd4.x, wd4.y, wd4.z, wd4.w};
        float v0 = p ? od[fk] : ev[fk];
#pragma unroll
        for (int i = 0; i < 16; ++i) acc[i] = fmaf(v0, wr[i], acc[i]);
      }
    }
    __syncthreads();
  }
  const float inv = 1.f / 512.f;
#pragma unroll
  for (int i = 0; i < 16; ++i) {
    int o = og * 16 + i;
    float s = fmaxf(acc[i] + r2bf[o], 0.f);
#pragma unroll
    for (int d = 32; d > 0; d >>= 1) s += __shfl_down(s, d, 64);
    if (tl == 0) atomicAdd(&combined[b * 512 + 2 * o + half], s * inv);
  }
}

// ---- fused D: conv1-d (class select, K=4, branchless 7-class table) + conv2-d + pool ----
// 1024 blocks: chunk in [0,32), b. dt[c][iu] = d1[c][tbase-1+iu], iu in [0,131).
__device__ __forceinline__ void dev_df(float* smem, const int* tok,
                                       const float* d1wf, const float* d1bf,
                                       const float* d2wf, const float* d2bf,
                                       float* dpws, int chunk, int b) {
  float* wds7 = smem;                 // 16*7*4 = 448 (class 6 = zeros)
  float* wd = smem + 448;             // 768
  int* cls = (int*)(smem + 1216);     // 136
  float (*dt)[132] = reinterpret_cast<float(*)[132]>(smem + 1352);  // 16x132
  float* c2 = smem + 3464;            // 16 rows, stride 133
  const int tid = threadIdx.x;
  const int tbase = chunk * 128;
  const int* tokb = tok + b * 4096;
  for (int f = tid; f < 448; f += 256) {
    int k = f & 3, rest = f >> 2, v = rest % 7, c = rest / 7;
    wds7[f] = (v < 6) ? d1wf[(c * 6 + v) * 4 + k] : 0.f;
  }
  for (int f = tid; f < 768; f += 256) wd[f] = d2wf[f];
  if (tid < 136) {
    int x = tbase - 3 + tid;
    int v = 6;
    if ((unsigned)x < 4096u) {
      int tk = tokb[x];
      if (tk >= 768) { v = tk - 768; v = v > 5 ? 5 : v; } else v = 6;
    }
    cls[tid] = v;
  }
  __syncthreads();
  for (int f = tid; f < 16 * 131; f += 256) {
    int iu = f % 131, c = f / 131;
    int x = tbase - 1 + iu;
    float v = 0.f;
    if (x >= 0 && x <= 4096) {
      float a = d1bf[c];
#pragma unroll
      for (int k = 0; k < 4; ++k) {
        a += wds7[(c * 7 + cls[iu + k]) * 4 + k];
      }
      v = fmaxf(a, 0.f);
    }
    dt[c][iu] = v;
  }
  __syncthreads();
  for (int idx = tid; idx < 16 * 129; idx += 256) {
    int o = idx / 129, tl = idx % 129;
    float a = d2bf[o];
    const float* ww = &wd[o * 48];
#pragma unroll 4
    for (int c = 0; c < 16; ++c) {
      a = fmaf(dt[c][tl], ww[c * 3 + 0],
          fmaf(dt[c][tl + 1], ww[c * 3 + 1],
          fmaf(dt[c][tl + 2], ww[c * 3 + 2], a)));
    }
    c2[o * 133 + tl] = fmaxf(a, 0.f);
  }
  __syncthreads();
  if (tid < 64) {
    int o = tid >> 2, qq = tid & 3;
    const float* row = c2 + o * 133 + 32 * qq;
    float s = 0.f;
#pragma unroll
    for (int j = 0; j < 33; ++j) s += row[j];
    dpws[(size_t)(b * 16 + o) * 128 + 4 * chunk + qq] = s * (1.f / 33.f);
  }
}

__global__ __launch_bounds__(256, 4) void k_fused(const int* __restrict__ tok,
                                                  const float* __restrict__ wb,
                                                  const float* __restrict__ wTh1,
                                                  const float* __restrict__ wTm1,
                                                  const u16* __restrict__ wh2b,
                                                  const u16* __restrict__ wh2l,
                                                  const u16* __restrict__ wm2b,
                                                  const u16* __restrict__ wm2l,
                                                  float* __restrict__ combined,
                                                  float* __restrict__ dpws) {
  __shared__ __align__(16) float smem[6896];   // 27584 B (r-family max)
  int bx = blockIdx.x;
  if (bx < 1024) {
    dev_hf(smem, tok, wTh1, wb + WB_H1B, wh2b, wh2l, wb + WB_H2B, combined,
           bx & 7, (bx >> 3) & 3, bx >> 5);
  } else if (bx < 2048) {
    int n = bx - 1024;
    dev_mf(smem, tok, wTm1, wb + WB_M1B, wm2b, wm2l, wb + WB_M2B, combined,
           n & 7, (n >> 3) & 3, n >> 5);
  } else if (bx < 2560) {
    int n = bx - 2048;
    dev_rf(smem, tok, wb + WB_R1W, wb + WB_R1B, wb + WB_R2W, wb + WB_R2B,
           combined, n & 15, n >> 4);
  } else {
    int n = bx - 2560;
    dev_df(smem, tok, wb + WB_D1W, wb + WB_D1B, wb + WB_D2W, wb + WB_D2B,
           dpws, n & 31, n >> 5);
  }
}

// ---------- FC (+ fused dynamics final pool) ----------
// 256 blocks: b = bx>>3, oct = bx&7; 64 outputs/block, 4 lanes per output.
__global__ __launch_bounds__(256) void k_fc(const float* __restrict__ combined,
                                            const float* __restrict__ dpws,
                                            const float* __restrict__ fcwf,
                                            const float* __restrict__ fcbf,
                                            float* __restrict__ featf,
                                            u16* __restrict__ featb) {
  const int bx = blockIdx.x;
  const int b = bx >> 3, oct = bx & 7;
  const int tid = threadIdx.x;
  __shared__ float cb[512];
  cb[tid] = combined[b * 512 + tid];
  if (tid < 128) {
    cb[256 + tid] = combined[b * 512 + 256 + tid];
  } else {
    int j = tid - 128;                 // [0,128) -> combined[384..512)
    int o = j >> 3, i0 = (j & 7) * 16;
    const float* row = dpws + (size_t)(b * 16 + o) * 128;
    float s = 0.f;
#pragma unroll
    for (int i = 0; i < 16; ++i) s += row[i0 + i];
    cb[384 + j] = s * (1.f / 16.f);
  }
  __syncthreads();
  const int oo = oct * 64 + (tid >> 2), part = tid & 3;
  float acc = 0.f;
  const float4* wr = (const float4*)(fcwf + (size_t)oo * 512 + part * 128);
#pragma unroll 8
  for (int j4 = 0; j4 < 32; ++j4) {
    float4 w = wr[j4];
    const float* c4 = &cb[part * 128 + j4 * 4];
    acc = fmaf(c4[0], w.x, acc);
    acc = fmaf(c4[1], w.y, acc);
    acc = fmaf(c4[2], w.z, acc);
    acc = fmaf(c4[3], w.w, acc);
  }
  acc += __shfl_xor(acc, 1, 64);
  acc += __shfl_xor(acc, 2, 64);
  if (part == 0) {
    float r = acc + fcbf[oo];
    featf[b * 512 + oo] = r;
    featb[b * 512 + oo] = f2bf(r);
  }
}

// ---------- broadcast (nontemporal; bf16 path uses all blocks) ----------
__global__ __launch_bounds__(256) void k_bcast(const int* __restrict__ flagp,
                                               const vf4* __restrict__ featf4,
                                               const vu4* __restrict__ featb4,
                                               vf4* __restrict__ outf,
                                               vu4* __restrict__ outb) {
  if (flagp[0]) {
    int base = blockIdx.x * 1024 + threadIdx.x;
#pragma unroll
    for (int s = 0; s < 4; ++s) {
      int g = base + s * 256;        // 16777216 vf4 total
      vf4 v = featf4[(g >> 19) * 128 + (g & 127)];
      __builtin_nontemporal_store(v, &outf[g]);
    }
  } else {
    int base = blockIdx.x * 512 + threadIdx.x;
#pragma unroll
    for (int s = 0; s < 2; ++s) {
      int g = base + s * 256;        // 8388608 vu4 total
      vu4 v = featb4[(g >> 18) * 64 + (g & 63)];
      __builtin_nontemporal_store(v, &outb[g]);
    }
  }
}

extern "C" void kernel_launch(void* const* d_in, const int* in_sizes, int n_in,
                              void* d_out, int out_size, void* d_ws, size_t ws_size,
                              hipStream_t stream) {
  if (ws_size < WS_NEEDED) return;

  const int* tokens = (const int*)d_in[0];
  const void* r1_w = d_in[1];  const void* r1_b = d_in[2];
  const void* r2_w = d_in[3];  const void* r2_b = d_in[4];
  const void* h1_w = d_in[5];  const void* h1_b = d_in[6];
  const void* h2_w = d_in[7];  const void* h2_b = d_in[8];
  const void* m1_w = d_in[9];  const void* m1_b = d_in[10];
  const void* m2_w = d_in[11]; const void* m2_b = d_in[12];
  const void* d1_w = d_in[13]; const void* d1_b = d_in[14];
  const void* d2_w = d_in[15]; const void* d2_b = d_in[16];
  const void* fc_w = d_in[17]; const void* fc_b = d_in[18];

  char* ws = (char*)d_ws;
  int*   flagp   = (int*)  (ws + OFF_FLAG);
  float* wb      = (float*)(ws + OFF_WB);
  float* wTh1    = (float*)(ws + OFF_WTH1);
  float* wTm1    = (float*)(ws + OFF_WTM1);
  float* combined= (float*)(ws + OFF_COMB);
  float* featf   = (float*)(ws + OFF_FEATF);
  u16*   featb   = (u16*)  (ws + OFF_FEATB);
  float* dpws    = (float*)(ws + OFF_DP);
  u16*   wh2b    = (u16*)  (ws + OFF_WH2B);
  u16*   wh2l    = (u16*)  (ws + OFF_WH2L);
  u16*   wm2b    = (u16*)  (ws + OFF_WM2B);
  u16*   wm2l    = (u16*)  (ws + OFF_WM2L);

  k_convert<<<1853, 256, 0, stream>>>(r1_w, r1_b, r2_w, r2_b, h1_w, h1_b, h2_w, h2_b,
                                      m1_w, m1_b, m2_w, m2_b, d1_w, d1_b, d2_w, d2_b,
                                      fc_w, fc_b, flagp, wb, wTh1, wTm1, combined,
                                      wh2b, wh2l, wm2b, wm2l);
  k_fused<<<3584, 256, 0, stream>>>(tokens, wb, wTh1, wTm1, wh2b, wh2l, wm2b, wm2l,
                                    combined, dpws);
  k_fc<<<256, 256, 0, stream>>>(combined, dpws, wb + WB_FCW, wb + WB_FCB, featf, featb);
  k_bcast<<<16384, 256, 0, stream>>>(flagp, (const vf4*)featf, (const vu4*)featb,
                                     (vf4*)d_out, (vu4*)d_out);
}